// Round 16
// baseline (287.229 us; speedup 1.0000x reference)
//
#include <hip/hip_runtime.h>
#include <cstdint>
#include <cstddef>

typedef unsigned short u16;
typedef unsigned int u32;
typedef __attribute__((ext_vector_type(8))) short s16x8;
typedef __attribute__((ext_vector_type(4))) float f32x4;

#define NB 4
#define NT 2048
#define ND 768
#define NH 12
#define NDH 64
#define NFF 3072
#define NM (NB*NT)   // 8192 rows

__device__ __forceinline__ u16 f2b(float f){
  union { float f; unsigned u; } c; c.f = f;
  unsigned r = c.u + 0x7fffu + ((c.u >> 16) & 1u);
  return (u16)(r >> 16);
}

__device__ __forceinline__ f32x4 mfma16(s16x8 a, s16x8 b, f32x4 c){
  return __builtin_amdgcn_mfma_f32_16x16x32_bf16(a, b, c, 0, 0, 0);
}

// async global->LDS, 16B per lane. LDS dest = wave-uniform base + lane*16.
__device__ __forceinline__ void stage16(u16* lds, const u16* g){
  __builtin_amdgcn_global_load_lds(
      (const __attribute__((address_space(1))) unsigned int*)g,
      (__attribute__((address_space(3))) unsigned int*)lds,
      16, 0, 0);
}

// erf via A&S 7.1.26 (|err|<1.5e-7): 1 expf + ~12 fma, ~3x cheaper than libm erff
__device__ __forceinline__ float gelu_f(float v){
  const float x = v * 0.70710678118654752f;
  const float ax = fabsf(x);
  const float t = 1.f / (1.f + 0.3275911f * ax);
  const float y = t * (0.254829592f + t * (-0.284496736f + t * (1.421413741f
                + t * (-1.453152027f + t * 1.061405429f))));
  float er = 1.f - y * __expf(-ax * ax);
  er = copysignf(er, x);
  return 0.5f * v * (1.f + er);
}

// ---------------- fused: 4x weight transpose->bf16 + LayerNorm1 (independent ops) ----------------
// blocks 0..6911: transpose tiles; blocks 6912..15103: LN1 rows. One launch, 256 thr.
__global__ __launch_bounds__(256) void pre_kernel(
    const float* __restrict__ w_qkv, const float* __restrict__ w_proj,
    const float* __restrict__ w_ff1, const float* __restrict__ w_ff2,
    u16* __restrict__ o_qkv, u16* __restrict__ o_proj,
    u16* __restrict__ o_ff1, u16* __restrict__ o_ff2,
    const float* __restrict__ x, const float* __restrict__ ln_g,
    const float* __restrict__ ln_b, u16* __restrict__ ln_out)
{
  const int t = threadIdx.x;
  if (blockIdx.x >= 6912) {
    // ---- LayerNorm (row = 768), fp32 in -> bf16 out ----
    const int row = blockIdx.x - 6912;
    const float* xr = x + (size_t)row * ND;
    float v0 = xr[t], v1 = xr[t + 256], v2 = xr[t + 512];
    float s = v0 + v1 + v2;
    float ss = v0*v0 + v1*v1 + v2*v2;
    #pragma unroll
    for (int o = 32; o; o >>= 1) { s += __shfl_xor(s, o, 64); ss += __shfl_xor(ss, o, 64); }
    __shared__ float red[8];
    const int w = t >> 6;
    if ((t & 63) == 0) { red[w] = s; red[4 + w] = ss; }
    __syncthreads();
    s  = red[0] + red[1] + red[2] + red[3];
    ss = red[4] + red[5] + red[6] + red[7];
    const float mu = s * (1.f / ND);
    const float var = ss * (1.f / ND) - mu * mu;
    const float rinv = rsqrtf(var + 1e-5f);
    u16* orow = ln_out + (size_t)row * ND;
    orow[t]       = f2b((v0 - mu) * rinv * ln_g[t]       + ln_b[t]);
    orow[t + 256] = f2b((v1 - mu) * rinv * ln_g[t + 256] + ln_b[t + 256]);
    orow[t + 512] = f2b((v2 - mu) * rinv * ln_g[t + 512] + ln_b[t + 512]);
    return;
  }
  // ---- transpose + convert: out[n][k] = in[k][n] ----
  int bid = blockIdx.x;
  const float* in; u16* out; int K, N, nx;
  if (bid < 1728)      { in = w_qkv;  out = o_qkv;  K = 768;  N = 2304; nx = 72; }
  else if ((bid -= 1728) < 576)  { in = w_proj; out = o_proj; K = 768;  N = 768;  nx = 24; }
  else if ((bid -= 576) < 2304)  { in = w_ff1;  out = o_ff1;  K = 768;  N = 3072; nx = 96; }
  else { bid -= 2304;              in = w_ff2;  out = o_ff2;  K = 3072; N = 768;  nx = 24; }
  const int n0 = (bid % nx) * 32, k0 = (bid / nx) * 32;

  __shared__ float tile[32][33];
  const int tx = t & 31, ty = t >> 5; // 32 x 8
  #pragma unroll
  for (int i = 0; i < 32; i += 8)
    tile[ty + i][tx] = in[(size_t)(k0 + ty + i) * N + n0 + tx];
  __syncthreads();
  #pragma unroll
  for (int i = 0; i < 32; i += 8)
    out[(size_t)(n0 + ty + i) * K + k0 + tx] = f2b(tile[tx][ty + i]);
}

// ---------------- LayerNorm (row = 768), fp32 in -> bf16 out (LN2) ----------------
__global__ __launch_bounds__(256) void ln_kernel(
    const float* __restrict__ x, const float* __restrict__ g,
    const float* __restrict__ b, u16* __restrict__ out)
{
  const int row = blockIdx.x;
  const int t = threadIdx.x;
  const float* xr = x + (size_t)row * ND;
  float v0 = xr[t], v1 = xr[t + 256], v2 = xr[t + 512];
  float s = v0 + v1 + v2;
  float ss = v0*v0 + v1*v1 + v2*v2;
  #pragma unroll
  for (int o = 32; o; o >>= 1) { s += __shfl_xor(s, o, 64); ss += __shfl_xor(ss, o, 64); }
  __shared__ float red[8];
  const int w = t >> 6;
  if ((t & 63) == 0) { red[w] = s; red[4 + w] = ss; }
  __syncthreads();
  s  = red[0] + red[1] + red[2] + red[3];
  ss = red[4] + red[5] + red[6] + red[7];
  const float mu = s * (1.f / ND);
  const float var = ss * (1.f / ND) - mu * mu;
  const float rinv = rsqrtf(var + 1e-5f);
  u16* orow = out + (size_t)row * ND;
  orow[t]       = f2b((v0 - mu) * rinv * g[t]       + b[t]);
  orow[t + 256] = f2b((v1 - mu) * rinv * g[t + 256] + b[t + 256]);
  orow[t + 512] = f2b((v2 - mu) * rinv * g[t + 512] + b[t + 512]);
}

// ---------------- GEMM: counted-vmcnt pipeline, triple-buffer LDS, chunk swizzle ----------------
// (round-8/11/13 measured configuration — best known)
// C[M][N] = A[M][K] * Bt[N][K]^T + bias, fused epilogue. BM in {128, 64}, BN = 128.
// EPI 0: qkv split-scatter to [B,H,T,DH] bf16 (o0=q scaled by 0.125, o1=k, o2=v)
// EPI 1: + res (x) -> fp32 o0
// EPI 2: gelu -> bf16 o0
// EPI 3: + res (x1) -> fp32 o0
template<int EPI, int BM>
__global__ __launch_bounds__(256, (BM == 128) ? 3 : 4) void gemm_bt(
    const u16* __restrict__ A, const u16* __restrict__ Bt,
    const float* __restrict__ bias, const float* __restrict__ res,
    void* __restrict__ o0, void* __restrict__ o1, void* __restrict__ o2,
    const int M, const int N, const int K)
{
  constexpr int MI = BM / 64;
  __shared__ u16 As[3][BM * 32];
  __shared__ u16 Bs[3][128 * 32];
  const int tid = threadIdx.x;
  const int lane = tid & 63, wid = tid >> 6;
  const int wr = wid >> 1, wc = wid & 1;
  const int lg = lane >> 4, lm = lane & 15;
  const int bm = blockIdx.x * BM, bn = blockIdx.y * 128;

  f32x4 acc[2 * MI][4] = {};

  const int srow = tid >> 2;
  const int schunk = (tid & 3) ^ ((tid >> 3) & 3);
  const u16* ApT = A  + (size_t)(bm + srow) * K + schunk * 8;
  const u16* BpT = Bt + (size_t)(bn + srow) * K + schunk * 8;
  const size_t rs64 = (size_t)64 * K;
  const int woff = wid * 512;
  const int fswz = (lm >> 1) & 3;

  const int nt = K >> 5;

  #pragma unroll
  for (int p = 0; p < 2; ++p) {
    const int k0 = p << 5;
    stage16(&As[p][woff], ApT + k0);
    if (BM == 128) stage16(&As[p][woff + 2048], ApT + rs64 + k0);
    stage16(&Bs[p][woff],        BpT + k0);
    stage16(&Bs[p][woff + 2048], BpT + rs64 + k0);
  }

  for (int t = 0; t < nt; ++t) {
    if (t < nt - 1) {
      if (BM == 128) asm volatile("s_waitcnt vmcnt(4)" ::: "memory");
      else           asm volatile("s_waitcnt vmcnt(3)" ::: "memory");
    } else {
      asm volatile("s_waitcnt vmcnt(0)" ::: "memory");
    }
    __builtin_amdgcn_s_barrier();
    __builtin_amdgcn_sched_barrier(0);
    if (t + 2 < nt) {
      const int k0 = (t + 2) << 5;
      const int wb = (t + 2) % 3;
      stage16(&As[wb][woff], ApT + k0);
      if (BM == 128) stage16(&As[wb][woff + 2048], ApT + rs64 + k0);
      stage16(&Bs[wb][woff],        BpT + k0);
      stage16(&Bs[wb][woff + 2048], BpT + rs64 + k0);
    }
    __builtin_amdgcn_sched_barrier(0);
    const int rb = t % 3;
    s16x8 af[2 * MI], bf[4];
    #pragma unroll
    for (int i = 0; i < 2 * MI; i++)
      af[i] = *(const s16x8*)&As[rb][(wr * (BM / 2) + i * 16 + lm) * 32 + ((lg ^ fswz) * 8)];
    #pragma unroll
    for (int j = 0; j < 4; j++)
      bf[j] = *(const s16x8*)&Bs[rb][(wc * 64 + j * 16 + lm) * 32 + ((lg ^ fswz) * 8)];
    #pragma unroll
    for (int i = 0; i < 2 * MI; i++)
      #pragma unroll
      for (int j = 0; j < 4; j++)
        acc[i][j] = mfma16(af[i], bf[j], acc[i][j]);
  }

  #pragma unroll
  for (int i = 0; i < 2 * MI; i++)
    #pragma unroll
    for (int j = 0; j < 4; j++) {
      const int col = bn + wc * 64 + j * 16 + lm;
      const float bb = bias[col];
      #pragma unroll
      for (int r = 0; r < 4; r++) {
        const int row = bm + wr * (BM / 2) + i * 16 + lg * 4 + r;
        float v = acc[i][j][r] + bb;
        if (EPI == 0) {
          u16* dst; int rem;
          if (col < ND)            { dst = (u16*)o0; rem = col; v *= 0.125f; }
          else if (col < 2 * ND)   { dst = (u16*)o1; rem = col - ND; }
          else                     { dst = (u16*)o2; rem = col - 2 * ND; }
          const int hh = rem >> 6, dh = rem & 63;
          const int bb2 = row >> 11, tt = row & 2047;
          dst[(((size_t)bb2 * NH + hh) * NT + tt) * NDH + dh] = f2b(v);
        } else if (EPI == 1) {
          ((float*)o0)[(size_t)row * ND + col] = v + res[(size_t)row * ND + col];
        } else if (EPI == 2) {
          ((u16*)o0)[(size_t)row * NFF + col] = f2b(gelu_f(v));
        } else {
          ((float*)o0)[(size_t)row * ND + col] = v + res[(size_t)row * ND + col];
        }
      }
    }
}

// ---------------- Flash attention, causal, swapped-QK^T, MERGED strips + defer-max ----------------
// Q pre-scaled by 0.125. Q,K,V: [B,H,T,DH] bf16. O: [B,T,D] bf16.
// Block: 256 thr (4 waves), strips si0 = p and si1 = 31-p in ONE pass over kv tiles.
// defer-max (T13): skip O-rescale when tile max within 8 of running max (P <= e^8,
// l is f32 -> safe; first tile m=-inf always rescales).
// Grid: (bh, pair) with bh FASTEST -> 16 blocks sharing a head's K/V on one XCD.
__global__ __launch_bounds__(256,3) void attn_kernel(
    const u16* __restrict__ Q, const u16* __restrict__ Kg,
    const u16* __restrict__ V, u16* __restrict__ O)
{
  const int p  = blockIdx.y;        // 0..15
  const int bh = blockIdx.x;        // b*H + h  (fastest-varying)
  const int b = bh / NH, h = bh % NH;
  const int tid = threadIdx.x;
  const int lane = tid & 63, w = tid >> 6;
  const int lg = lane >> 4, lm = lane & 15;
  const int sr = tid >> 3;          // 0..31 (staging row)
  const int sc = (tid & 7) * 8;     // 0..56 (staging col)

  __shared__ u16 Ks[64 * 64];
  __shared__ u16 Vt[64 * 64];
  __shared__ u16 Ps[4][16 * 64];

  const u16* Qb = Q  + (size_t)bh * NT * NDH;
  const u16* Kb = Kg + (size_t)bh * NT * NDH;
  const u16* Vb = V  + (size_t)bh * NT * NDH;

  const int si0 = p, si1 = 31 - p;
  const int q00 = si0 * 64, q01 = si1 * 64;
  const int ktmax = si1;

  const s16x8 q0a = *(const s16x8*)&Qb[(size_t)(q00 + w * 16 + lm) * NDH + lg * 8];
  const s16x8 q0b = *(const s16x8*)&Qb[(size_t)(q00 + w * 16 + lm) * NDH + 32 + lg * 8];
  const s16x8 q1a = *(const s16x8*)&Qb[(size_t)(q01 + w * 16 + lm) * NDH + lg * 8];
  const s16x8 q1b = *(const s16x8*)&Qb[(size_t)(q01 + w * 16 + lm) * NDH + 32 + lg * 8];

  f32x4 oacc0[4] = {}, oacc1[4] = {};
  float m0 = -INFINITY, l0 = 0.f, m1 = -INFINITY, l1 = 0.f;

  auto do_strip = [&](const s16x8& qa, const s16x8& qb, f32x4* oacc,
                      float& m, float& l, bool diag) {
    f32x4 sv[4];
    #pragma unroll
    for (int n = 0; n < 4; ++n) {
      const int krow = (n * 16 + lm) * 64;
      const int swz = (lm & 7) << 3;
      s16x8 kf0 = *(const s16x8*)&Ks[krow + ((lg * 8) ^ swz)];
      s16x8 kf1 = *(const s16x8*)&Ks[krow + ((32 + lg * 8) ^ swz)];
      f32x4 s4 = {};
      s4 = mfma16(kf0, qa, s4);
      s4 = mfma16(kf1, qb, s4);
      sv[n] = s4;
    }
    if (diag) {
      #pragma unroll
      for (int n = 0; n < 4; ++n)
        #pragma unroll
        for (int r = 0; r < 4; ++r)
          if (n * 16 + lg * 4 + r > w * 16 + lm) sv[n][r] = -INFINITY;
    }
    float mx = -INFINITY;
    #pragma unroll
    for (int n = 0; n < 4; ++n)
      #pragma unroll
      for (int r = 0; r < 4; ++r) mx = fmaxf(mx, sv[n][r]);
    mx = fmaxf(mx, __shfl_xor(mx, 16));
    mx = fmaxf(mx, __shfl_xor(mx, 32));

    // defer-max: if tile max within 8 of running max (all rows), keep m (P <= e^8)
    const bool defer = __all(mx - m <= 8.f);
    float alpha = 1.f;
    if (!defer) {
      const float mnew = fmaxf(m, mx);
      alpha = __expf(m - mnew);
      m = mnew;
    }

    float rs = 0.f;
    u32 pk[4][2];
    #pragma unroll
    for (int n = 0; n < 4; ++n) {
      const float p0 = __expf(sv[n][0] - m);
      const float p1 = __expf(sv[n][1] - m);
      const float p2 = __expf(sv[n][2] - m);
      const float p3 = __expf(sv[n][3] - m);
      rs += (p0 + p1) + (p2 + p3);
      pk[n][0] = (u32)f2b(p0) | ((u32)f2b(p1) << 16);
      pk[n][1] = (u32)f2b(p2) | ((u32)f2b(p3) << 16);
    }
    rs += __shfl_xor(rs, 16);
    rs += __shfl_xor(rs, 32);

    #pragma unroll
    for (int n = 0; n < 4; ++n) {
      const int idx0 = lm * 64 + ((n * 16 + lg * 4) ^ ((lm & 7) << 3));
      *(u32*)&Ps[w][idx0] = pk[n][0];
      *(u32*)&Ps[w][idx0 + 2] = pk[n][1];
    }

    if (!defer) {
      l = l * alpha + rs;
      float av[4];
      #pragma unroll
      for (int r = 0; r < 4; ++r) av[r] = __shfl(alpha, lg * 4 + r);
      #pragma unroll
      for (int d = 0; d < 4; ++d)
        #pragma unroll
        for (int r = 0; r < 4; ++r) oacc[d][r] *= av[r];
    } else {
      l += rs;
    }

    #pragma unroll
    for (int kh = 0; kh < 2; ++kh) {
      const s16x8 pf = *(const s16x8*)&Ps[w][lm * 64 + ((kh * 32 + lg * 8) ^ ((lm & 7) << 3))];
      #pragma unroll
      for (int dt = 0; dt < 4; ++dt) {
        const int g = ((2 * dt + (lm >> 3)) ^ (lm & 7)) & 7;
        const s16x8 vf = *(const s16x8*)&Vt[(dt * 16 + lm) * 64 + (((kh * 4 + lg) ^ g) << 3)];
        oacc[dt] = mfma16(pf, vf, oacc[dt]);
      }
    }
  };

  s16x8 kva = *(const s16x8*)&Kb[(size_t)sr * NDH + sc];
  s16x8 kvb = *(const s16x8*)&Kb[(size_t)(sr + 32) * NDH + sc];
  s16x8 vva = *(const s16x8*)&Vb[(size_t)sr * NDH + sc];
  s16x8 vvb = *(const s16x8*)&Vb[(size_t)(sr + 32) * NDH + sc];

  for (int kt = 0; kt <= ktmax; ++kt) {
    __syncthreads();
    *(s16x8*)&Ks[sr * 64 + (sc ^ ((sr & 7) << 3))] = kva;
    *(s16x8*)&Ks[(sr + 32) * 64 + (sc ^ ((sr & 7) << 3))] = kvb;
    #pragma unroll
    for (int e = 0; e < 8; ++e)
      Vt[(sc + e) * 64 + (sr ^ ((((tid & 7) ^ e)) << 3))] = (u16)vva[e];
    #pragma unroll
    for (int e = 0; e < 8; ++e)
      Vt[(sc + e) * 64 + ((sr + 32) ^ ((((tid & 7) ^ e)) << 3))] = (u16)vvb[e];
    __syncthreads();

    if (kt < ktmax) {
      const u16* Kn = Kb + (size_t)(kt + 1) * 64 * NDH;
      const u16* Vn = Vb + (size_t)(kt + 1) * 64 * NDH;
      kva = *(const s16x8*)&Kn[(size_t)sr * NDH + sc];
      kvb = *(const s16x8*)&Kn[(size_t)(sr + 32) * NDH + sc];
      vva = *(const s16x8*)&Vn[(size_t)sr * NDH + sc];
      vvb = *(const s16x8*)&Vn[(size_t)(sr + 32) * NDH + sc];
    }

    do_strip(q1a, q1b, oacc1, m1, l1, kt == si1);
    if (kt <= si0) do_strip(q0a, q0b, oacc0, m0, l0, kt == si0);
  }

  {
    float lv[4];
    #pragma unroll
    for (int r = 0; r < 4; ++r) lv[r] = 1.f / __shfl(l0, lg * 4 + r);
    #pragma unroll
    for (int dt = 0; dt < 4; ++dt)
      #pragma unroll
      for (int r = 0; r < 4; ++r) {
        const int qg = q00 + w * 16 + lg * 4 + r;
        O[((size_t)b * NT + qg) * ND + h * NDH + dt * 16 + lm] = f2b(oacc0[dt][r] * lv[r]);
      }
  }
  {
    float lv[4];
    #pragma unroll
    for (int r = 0; r < 4; ++r) lv[r] = 1.f / __shfl(l1, lg * 4 + r);
    #pragma unroll
    for (int dt = 0; dt < 4; ++dt)
      #pragma unroll
      for (int r = 0; r < 4; ++r) {
        const int qg = q01 + w * 16 + lg * 4 + r;
        O[((size_t)b * NT + qg) * ND + h * NDH + dt * 16 + lm] = f2b(oacc1[dt][r] * lv[r]);
      }
  }
}

// ---------------- launch ----------------
extern "C" void kernel_launch(void* const* d_in, const int* in_sizes, int n_in,
                              void* d_out, int out_size, void* d_ws, size_t ws_size,
                              hipStream_t stream)
{
  const float* x      = (const float*)d_in[0];
  const float* ln1_g  = (const float*)d_in[1];
  const float* ln1_b  = (const float*)d_in[2];
  const float* w_qkv  = (const float*)d_in[3];
  const float* b_qkv  = (const float*)d_in[4];
  const float* w_proj = (const float*)d_in[5];
  const float* b_proj = (const float*)d_in[6];
  const float* ln2_g  = (const float*)d_in[7];
  const float* ln2_b  = (const float*)d_in[8];
  const float* w_ff1  = (const float*)d_in[9];
  const float* b_ff1  = (const float*)d_in[10];
  const float* w_ff2  = (const float*)d_in[11];
  const float* b_ff2  = (const float*)d_in[12];

  char* ws = (char*)d_ws;
  u16*   wt_qkv = (u16*)(ws + 0);          //  2304x768 bf16
  u16*   wt_proj= (u16*)(ws + 3538944);    //   768x768
  u16*   wt_ff1 = (u16*)(ws + 4718592);    //  3072x768
  u16*   wt_ff2 = (u16*)(ws + 9437184);    //   768x3072
  u16*   hbuf   = (u16*)(ws + 14155776);   //  8192x768 bf16 (LN1 out)
  u16*   qbuf   = (u16*)(ws + 26738688);   //  [B,H,T,DH]
  u16*   kbuf   = (u16*)(ws + 39321600);
  u16*   vbuf   = (u16*)(ws + 51904512);
  u16*   aobuf  = (u16*)(ws + 64487424);   //  8192x768 bf16 (attn out)
  float* x1     = (float*)(ws + 77070336); //  8192x768 fp32
  u16*   h2buf  = (u16*)(ws + 102236160);  //  8192x768 bf16 (LN2 out)
  u16*   ff1buf = hbuf;                    //  8192x3072 bf16, aliases h/q/k/v (dead by then)

  pre_kernel<<<6912 + NM, 256, 0, stream>>>(w_qkv, w_proj, w_ff1, w_ff2,
                                            wt_qkv, wt_proj, wt_ff1, wt_ff2,
                                            x, ln1_g, ln1_b, hbuf);
  gemm_bt<0,128><<<dim3(NM/128, 2304/128), 256, 0, stream>>>(hbuf, wt_qkv, b_qkv, nullptr,
                                                             qbuf, kbuf, vbuf, NM, 2304, ND);
  attn_kernel<<<dim3(NB*NH, 16), 256, 0, stream>>>(qbuf, kbuf, vbuf, aobuf);
  gemm_bt<1,64><<<dim3(NM/64, ND/128), 256, 0, stream>>>(aobuf, wt_proj, b_proj, x,
                                                         x1, nullptr, nullptr, NM, ND, ND);
  ln_kernel<<<NM, 256, 0, stream>>>(x1, ln2_g, ln2_b, h2buf);
  gemm_bt<2,128><<<dim3(NM/128, NFF/128), 256, 0, stream>>>(h2buf, wt_ff1, b_ff1, nullptr,
                                                            ff1buf, nullptr, nullptr, NM, NFF, ND);
  gemm_bt<3,64><<<dim3(NM/64, ND/128), 256, 0, stream>>>(ff1buf, wt_ff2, b_ff2, x1,
                                                         d_out, nullptr, nullptr, NM, ND, NFF);
}

// Round 17
// 287.089 us; speedup vs baseline: 1.0005x; 1.0005x over previous
//
#include <hip/hip_runtime.h>
#include <cstdint>
#include <cstddef>

typedef unsigned short u16;
typedef unsigned int u32;
typedef __attribute__((ext_vector_type(8))) short s16x8;
typedef __attribute__((ext_vector_type(4))) float f32x4;

#define NB 4
#define NT 2048
#define ND 768
#define NH 12
#define NDH 64
#define NFF 3072
#define NM (NB*NT)   // 8192 rows

__device__ __forceinline__ u16 f2b(float f){
  union { float f; unsigned u; } c; c.f = f;
  unsigned r = c.u + 0x7fffu + ((c.u >> 16) & 1u);
  return (u16)(r >> 16);
}

__device__ __forceinline__ f32x4 mfma16(s16x8 a, s16x8 b, f32x4 c){
  return __builtin_amdgcn_mfma_f32_16x16x32_bf16(a, b, c, 0, 0, 0);
}

// async global->LDS, 16B per lane. LDS dest = wave-uniform base + lane*16.
__device__ __forceinline__ void stage16(u16* lds, const u16* g){
  __builtin_amdgcn_global_load_lds(
      (const __attribute__((address_space(1))) unsigned int*)g,
      (__attribute__((address_space(3))) unsigned int*)lds,
      16, 0, 0);
}

// erf via A&S 7.1.26 (|err|<1.5e-7): 1 expf + ~12 fma, ~3x cheaper than libm erff
__device__ __forceinline__ float gelu_f(float v){
  const float x = v * 0.70710678118654752f;
  const float ax = fabsf(x);
  const float t = 1.f / (1.f + 0.3275911f * ax);
  const float y = t * (0.254829592f + t * (-0.284496736f + t * (1.421413741f
                + t * (-1.453152027f + t * 1.061405429f))));
  float er = 1.f - y * __expf(-ax * ax);
  er = copysignf(er, x);
  return 0.5f * v * (1.f + er);
}

// ---------------- fused: 4x weight transpose->bf16 + LayerNorm1 (independent ops) ----------------
// blocks 0..6911: transpose tiles; blocks 6912..15103: LN1 rows. One launch, 256 thr.
__global__ __launch_bounds__(256) void pre_kernel(
    const float* __restrict__ w_qkv, const float* __restrict__ w_proj,
    const float* __restrict__ w_ff1, const float* __restrict__ w_ff2,
    u16* __restrict__ o_qkv, u16* __restrict__ o_proj,
    u16* __restrict__ o_ff1, u16* __restrict__ o_ff2,
    const float* __restrict__ x, const float* __restrict__ ln_g,
    const float* __restrict__ ln_b, u16* __restrict__ ln_out)
{
  const int t = threadIdx.x;
  if (blockIdx.x >= 6912) {
    // ---- LayerNorm (row = 768), fp32 in -> bf16 out ----
    const int row = blockIdx.x - 6912;
    const float* xr = x + (size_t)row * ND;
    float v0 = xr[t], v1 = xr[t + 256], v2 = xr[t + 512];
    float s = v0 + v1 + v2;
    float ss = v0*v0 + v1*v1 + v2*v2;
    #pragma unroll
    for (int o = 32; o; o >>= 1) { s += __shfl_xor(s, o, 64); ss += __shfl_xor(ss, o, 64); }
    __shared__ float red[8];
    const int w = t >> 6;
    if ((t & 63) == 0) { red[w] = s; red[4 + w] = ss; }
    __syncthreads();
    s  = red[0] + red[1] + red[2] + red[3];
    ss = red[4] + red[5] + red[6] + red[7];
    const float mu = s * (1.f / ND);
    const float var = ss * (1.f / ND) - mu * mu;
    const float rinv = rsqrtf(var + 1e-5f);
    u16* orow = ln_out + (size_t)row * ND;
    orow[t]       = f2b((v0 - mu) * rinv * ln_g[t]       + ln_b[t]);
    orow[t + 256] = f2b((v1 - mu) * rinv * ln_g[t + 256] + ln_b[t + 256]);
    orow[t + 512] = f2b((v2 - mu) * rinv * ln_g[t + 512] + ln_b[t + 512]);
    return;
  }
  // ---- transpose + convert: out[n][k] = in[k][n] ----
  int bid = blockIdx.x;
  const float* in; u16* out; int K, N, nx;
  if (bid < 1728)      { in = w_qkv;  out = o_qkv;  K = 768;  N = 2304; nx = 72; }
  else if ((bid -= 1728) < 576)  { in = w_proj; out = o_proj; K = 768;  N = 768;  nx = 24; }
  else if ((bid -= 576) < 2304)  { in = w_ff1;  out = o_ff1;  K = 768;  N = 3072; nx = 96; }
  else { bid -= 2304;              in = w_ff2;  out = o_ff2;  K = 3072; N = 768;  nx = 24; }
  const int n0 = (bid % nx) * 32, k0 = (bid / nx) * 32;

  __shared__ float tile[32][33];
  const int tx = t & 31, ty = t >> 5; // 32 x 8
  #pragma unroll
  for (int i = 0; i < 32; i += 8)
    tile[ty + i][tx] = in[(size_t)(k0 + ty + i) * N + n0 + tx];
  __syncthreads();
  #pragma unroll
  for (int i = 0; i < 32; i += 8)
    out[(size_t)(n0 + ty + i) * K + k0 + tx] = f2b(tile[tx][ty + i]);
}

// ---------------- LayerNorm (row = 768), fp32 in -> bf16 out (LN2) ----------------
__global__ __launch_bounds__(256) void ln_kernel(
    const float* __restrict__ x, const float* __restrict__ g,
    const float* __restrict__ b, u16* __restrict__ out)
{
  const int row = blockIdx.x;
  const int t = threadIdx.x;
  const float* xr = x + (size_t)row * ND;
  float v0 = xr[t], v1 = xr[t + 256], v2 = xr[t + 512];
  float s = v0 + v1 + v2;
  float ss = v0*v0 + v1*v1 + v2*v2;
  #pragma unroll
  for (int o = 32; o; o >>= 1) { s += __shfl_xor(s, o, 64); ss += __shfl_xor(ss, o, 64); }
  __shared__ float red[8];
  const int w = t >> 6;
  if ((t & 63) == 0) { red[w] = s; red[4 + w] = ss; }
  __syncthreads();
  s  = red[0] + red[1] + red[2] + red[3];
  ss = red[4] + red[5] + red[6] + red[7];
  const float mu = s * (1.f / ND);
  const float var = ss * (1.f / ND) - mu * mu;
  const float rinv = rsqrtf(var + 1e-5f);
  u16* orow = out + (size_t)row * ND;
  orow[t]       = f2b((v0 - mu) * rinv * g[t]       + b[t]);
  orow[t + 256] = f2b((v1 - mu) * rinv * g[t + 256] + b[t + 256]);
  orow[t + 512] = f2b((v2 - mu) * rinv * g[t + 512] + b[t + 512]);
}

// ---------------- GEMM: counted-vmcnt pipeline, triple-buffer LDS, chunk swizzle ----------------
// (round-8/11/13 measured configuration — best known)
// C[M][N] = A[M][K] * Bt[N][K]^T + bias, fused epilogue. BM in {128, 64}, BN = 128.
// EPI 0: qkv split-scatter to [B,H,T,DH] bf16 (o0=q scaled by 0.125, o1=k, o2=v)
// EPI 1: + res (x) -> fp32 o0
// EPI 3: + res (x1) -> fp32 o0
template<int EPI, int BM>
__global__ __launch_bounds__(256, (BM == 128) ? 3 : 4) void gemm_bt(
    const u16* __restrict__ A, const u16* __restrict__ Bt,
    const float* __restrict__ bias, const float* __restrict__ res,
    void* __restrict__ o0, void* __restrict__ o1, void* __restrict__ o2,
    const int M, const int N, const int K)
{
  constexpr int MI = BM / 64;
  __shared__ u16 As[3][BM * 32];
  __shared__ u16 Bs[3][128 * 32];
  const int tid = threadIdx.x;
  const int lane = tid & 63, wid = tid >> 6;
  const int wr = wid >> 1, wc = wid & 1;
  const int lg = lane >> 4, lm = lane & 15;
  const int bm = blockIdx.x * BM, bn = blockIdx.y * 128;

  f32x4 acc[2 * MI][4] = {};

  const int srow = tid >> 2;
  const int schunk = (tid & 3) ^ ((tid >> 3) & 3);
  const u16* ApT = A  + (size_t)(bm + srow) * K + schunk * 8;
  const u16* BpT = Bt + (size_t)(bn + srow) * K + schunk * 8;
  const size_t rs64 = (size_t)64 * K;
  const int woff = wid * 512;
  const int fswz = (lm >> 1) & 3;

  const int nt = K >> 5;

  #pragma unroll
  for (int p = 0; p < 2; ++p) {
    const int k0 = p << 5;
    stage16(&As[p][woff], ApT + k0);
    if (BM == 128) stage16(&As[p][woff + 2048], ApT + rs64 + k0);
    stage16(&Bs[p][woff],        BpT + k0);
    stage16(&Bs[p][woff + 2048], BpT + rs64 + k0);
  }

  for (int t = 0; t < nt; ++t) {
    if (t < nt - 1) {
      if (BM == 128) asm volatile("s_waitcnt vmcnt(4)" ::: "memory");
      else           asm volatile("s_waitcnt vmcnt(3)" ::: "memory");
    } else {
      asm volatile("s_waitcnt vmcnt(0)" ::: "memory");
    }
    __builtin_amdgcn_s_barrier();
    __builtin_amdgcn_sched_barrier(0);
    if (t + 2 < nt) {
      const int k0 = (t + 2) << 5;
      const int wb = (t + 2) % 3;
      stage16(&As[wb][woff], ApT + k0);
      if (BM == 128) stage16(&As[wb][woff + 2048], ApT + rs64 + k0);
      stage16(&Bs[wb][woff],        BpT + k0);
      stage16(&Bs[wb][woff + 2048], BpT + rs64 + k0);
    }
    __builtin_amdgcn_sched_barrier(0);
    const int rb = t % 3;
    s16x8 af[2 * MI], bf[4];
    #pragma unroll
    for (int i = 0; i < 2 * MI; i++)
      af[i] = *(const s16x8*)&As[rb][(wr * (BM / 2) + i * 16 + lm) * 32 + ((lg ^ fswz) * 8)];
    #pragma unroll
    for (int j = 0; j < 4; j++)
      bf[j] = *(const s16x8*)&Bs[rb][(wc * 64 + j * 16 + lm) * 32 + ((lg ^ fswz) * 8)];
    #pragma unroll
    for (int i = 0; i < 2 * MI; i++)
      #pragma unroll
      for (int j = 0; j < 4; j++)
        acc[i][j] = mfma16(af[i], bf[j], acc[i][j]);
  }

  #pragma unroll
  for (int i = 0; i < 2 * MI; i++)
    #pragma unroll
    for (int j = 0; j < 4; j++) {
      const int col = bn + wc * 64 + j * 16 + lm;
      const float bb = bias[col];
      #pragma unroll
      for (int r = 0; r < 4; r++) {
        const int row = bm + wr * (BM / 2) + i * 16 + lg * 4 + r;
        float v = acc[i][j][r] + bb;
        if (EPI == 0) {
          u16* dst; int rem;
          if (col < ND)            { dst = (u16*)o0; rem = col; v *= 0.125f; }
          else if (col < 2 * ND)   { dst = (u16*)o1; rem = col - ND; }
          else                     { dst = (u16*)o2; rem = col - 2 * ND; }
          const int hh = rem >> 6, dh = rem & 63;
          const int bb2 = row >> 11, tt = row & 2047;
          dst[(((size_t)bb2 * NH + hh) * NT + tt) * NDH + dh] = f2b(v);
        } else if (EPI == 1) {
          ((float*)o0)[(size_t)row * ND + col] = v + res[(size_t)row * ND + col];
        } else {
          ((float*)o0)[(size_t)row * ND + col] = v + res[(size_t)row * ND + col];
        }
      }
    }
}

// ---------------- FF1 GEMM: 8-wave 128x256, counted-vmcnt triple-buffer, gelu epilogue ----------
// Same schedule/swizzle as gemm_bt, widened: 512 thr = 8 waves (2 row-halves x 4 col-quarters),
// wave output 64x64. LDS 72 KB -> 2 blocks/CU x 8 waves = 16 waves/CU (vs 10 at BM=128/BN=128).
// Per wave per K-step: 16 MFMA, 8 ds_read_b128, 3 stage16 (1 A + 2 B); vmcnt(3) counted.
__global__ __launch_bounds__(512, 4) void gemm_wide(
    const u16* __restrict__ A, const u16* __restrict__ Bt,
    const float* __restrict__ bias, u16* __restrict__ o0,
    const int K)
{
  __shared__ u16 As[3][128 * 32];   // 24 KB
  __shared__ u16 Bs[3][256 * 32];   // 48 KB
  const int tid = threadIdx.x;
  const int lane = tid & 63, wid = tid >> 6;   // 8 waves
  const int wr = wid >> 2, wc = wid & 3;       // 2 x 4 wave grid
  const int lg = lane >> 4, lm = lane & 15;
  const int bm = blockIdx.x * 128, bn = blockIdx.y * 256;

  f32x4 acc[4][4] = {};

  // staging: 512 threads cover 128 rows x 4 chunks; source chunk pre-swizzled.
  // (tid>>3)&3 == (srow>>1)&3 matches read-side fswz=(lm>>1)&3 for both B halves
  // (row offsets 0 and 128 are multiples of 4 in (row>>1)&3 terms -> key unchanged).
  const int srow = tid >> 2;                   // 0..127
  const int schunk = (tid & 3) ^ ((tid >> 3) & 3);
  const u16* ApT = A  + (size_t)(bm + srow) * K + schunk * 8;
  const u16* BpT = Bt + (size_t)(bn + srow) * K + schunk * 8;
  const size_t rs128 = (size_t)128 * K;
  const int woff = wid * 512;                  // wave-uniform LDS base (16 rows x 32 u16)
  const int fswz = (lm >> 1) & 3;

  const int nt = K >> 5;

  #pragma unroll
  for (int p = 0; p < 2; ++p) {
    const int k0 = p << 5;
    stage16(&As[p][woff],        ApT + k0);
    stage16(&Bs[p][woff],        BpT + k0);
    stage16(&Bs[p][woff + 4096], BpT + rs128 + k0);
  }

  for (int t = 0; t < nt; ++t) {
    if (t < nt - 1) asm volatile("s_waitcnt vmcnt(3)" ::: "memory");
    else            asm volatile("s_waitcnt vmcnt(0)" ::: "memory");
    __builtin_amdgcn_s_barrier();
    __builtin_amdgcn_sched_barrier(0);
    if (t + 2 < nt) {
      const int k0 = (t + 2) << 5;
      const int wb = (t + 2) % 3;
      stage16(&As[wb][woff],        ApT + k0);
      stage16(&Bs[wb][woff],        BpT + k0);
      stage16(&Bs[wb][woff + 4096], BpT + rs128 + k0);
    }
    __builtin_amdgcn_sched_barrier(0);
    const int rb = t % 3;
    s16x8 af[4], bf[4];
    #pragma unroll
    for (int i = 0; i < 4; i++)
      af[i] = *(const s16x8*)&As[rb][(wr * 64 + i * 16 + lm) * 32 + ((lg ^ fswz) * 8)];
    #pragma unroll
    for (int j = 0; j < 4; j++)
      bf[j] = *(const s16x8*)&Bs[rb][(wc * 64 + j * 16 + lm) * 32 + ((lg ^ fswz) * 8)];
    #pragma unroll
    for (int i = 0; i < 4; i++)
      #pragma unroll
      for (int j = 0; j < 4; j++)
        acc[i][j] = mfma16(af[i], bf[j], acc[i][j]);
  }

  #pragma unroll
  for (int i = 0; i < 4; i++)
    #pragma unroll
    for (int j = 0; j < 4; j++) {
      const int col = bn + wc * 64 + j * 16 + lm;
      const float bb = bias[col];
      #pragma unroll
      for (int r = 0; r < 4; r++) {
        const int row = bm + wr * 64 + i * 16 + lg * 4 + r;
        o0[(size_t)row * NFF + col] = f2b(gelu_f(acc[i][j][r] + bb));
      }
    }
}

// ---------------- Flash attention, causal, swapped-QK^T, MERGED strips + defer-max ----------------
// Q pre-scaled by 0.125. Q,K,V: [B,H,T,DH] bf16. O: [B,T,D] bf16.
// Block: 256 thr (4 waves), strips si0 = p and si1 = 31-p in ONE pass over kv tiles.
// defer-max (T13): skip O-rescale when tile max within 8 of running max.
// Grid: (bh, pair) with bh FASTEST -> 16 blocks sharing a head's K/V on one XCD.
__global__ __launch_bounds__(256,3) void attn_kernel(
    const u16* __restrict__ Q, const u16* __restrict__ Kg,
    const u16* __restrict__ V, u16* __restrict__ O)
{
  const int p  = blockIdx.y;        // 0..15
  const int bh = blockIdx.x;        // b*H + h  (fastest-varying)
  const int b = bh / NH, h = bh % NH;
  const int tid = threadIdx.x;
  const int lane = tid & 63, w = tid >> 6;
  const int lg = lane >> 4, lm = lane & 15;
  const int sr = tid >> 3;          // 0..31 (staging row)
  const int sc = (tid & 7) * 8;     // 0..56 (staging col)

  __shared__ u16 Ks[64 * 64];
  __shared__ u16 Vt[64 * 64];
  __shared__ u16 Ps[4][16 * 64];

  const u16* Qb = Q  + (size_t)bh * NT * NDH;
  const u16* Kb = Kg + (size_t)bh * NT * NDH;
  const u16* Vb = V  + (size_t)bh * NT * NDH;

  const int si0 = p, si1 = 31 - p;
  const int q00 = si0 * 64, q01 = si1 * 64;
  const int ktmax = si1;

  const s16x8 q0a = *(const s16x8*)&Qb[(size_t)(q00 + w * 16 + lm) * NDH + lg * 8];
  const s16x8 q0b = *(const s16x8*)&Qb[(size_t)(q00 + w * 16 + lm) * NDH + 32 + lg * 8];
  const s16x8 q1a = *(const s16x8*)&Qb[(size_t)(q01 + w * 16 + lm) * NDH + lg * 8];
  const s16x8 q1b = *(const s16x8*)&Qb[(size_t)(q01 + w * 16 + lm) * NDH + 32 + lg * 8];

  f32x4 oacc0[4] = {}, oacc1[4] = {};
  float m0 = -INFINITY, l0 = 0.f, m1 = -INFINITY, l1 = 0.f;

  auto do_strip = [&](const s16x8& qa, const s16x8& qb, f32x4* oacc,
                      float& m, float& l, bool diag) {
    f32x4 sv[4];
    #pragma unroll
    for (int n = 0; n < 4; ++n) {
      const int krow = (n * 16 + lm) * 64;
      const int swz = (lm & 7) << 3;
      s16x8 kf0 = *(const s16x8*)&Ks[krow + ((lg * 8) ^ swz)];
      s16x8 kf1 = *(const s16x8*)&Ks[krow + ((32 + lg * 8) ^ swz)];
      f32x4 s4 = {};
      s4 = mfma16(kf0, qa, s4);
      s4 = mfma16(kf1, qb, s4);
      sv[n] = s4;
    }
    if (diag) {
      #pragma unroll
      for (int n = 0; n < 4; ++n)
        #pragma unroll
        for (int r = 0; r < 4; ++r)
          if (n * 16 + lg * 4 + r > w * 16 + lm) sv[n][r] = -INFINITY;
    }
    float mx = -INFINITY;
    #pragma unroll
    for (int n = 0; n < 4; ++n)
      #pragma unroll
      for (int r = 0; r < 4; ++r) mx = fmaxf(mx, sv[n][r]);
    mx = fmaxf(mx, __shfl_xor(mx, 16));
    mx = fmaxf(mx, __shfl_xor(mx, 32));

    const bool defer = __all(mx - m <= 8.f);
    float alpha = 1.f;
    if (!defer) {
      const float mnew = fmaxf(m, mx);
      alpha = __expf(m - mnew);
      m = mnew;
    }

    float rs = 0.f;
    u32 pk[4][2];
    #pragma unroll
    for (int n = 0; n < 4; ++n) {
      const float p0 = __expf(sv[n][0] - m);
      const float p1 = __expf(sv[n][1] - m);
      const float p2 = __expf(sv[n][2] - m);
      const float p3 = __expf(sv[n][3] - m);
      rs += (p0 + p1) + (p2 + p3);
      pk[n][0] = (u32)f2b(p0) | ((u32)f2b(p1) << 16);
      pk[n][1] = (u32)f2b(p2) | ((u32)f2b(p3) << 16);
    }
    rs += __shfl_xor(rs, 16);
    rs += __shfl_xor(rs, 32);

    #pragma unroll
    for (int n = 0; n < 4; ++n) {
      const int idx0 = lm * 64 + ((n * 16 + lg * 4) ^ ((lm & 7) << 3));
      *(u32*)&Ps[w][idx0] = pk[n][0];
      *(u32*)&Ps[w][idx0 + 2] = pk[n][1];
    }

    if (!defer) {
      l = l * alpha + rs;
      float av[4];
      #pragma unroll
      for (int r = 0; r < 4; ++r) av[r] = __shfl(alpha, lg * 4 + r);
      #pragma unroll
      for (int d = 0; d < 4; ++d)
        #pragma unroll
        for (int r = 0; r < 4; ++r) oacc[d][r] *= av[r];
    } else {
      l += rs;
    }

    #pragma unroll
    for (int kh = 0; kh < 2; ++kh) {
      const s16x8 pf = *(const s16x8*)&Ps[w][lm * 64 + ((kh * 32 + lg * 8) ^ ((lm & 7) << 3))];
      #pragma unroll
      for (int dt = 0; dt < 4; ++dt) {
        const int g = ((2 * dt + (lm >> 3)) ^ (lm & 7)) & 7;
        const s16x8 vf = *(const s16x8*)&Vt[(dt * 16 + lm) * 64 + (((kh * 4 + lg) ^ g) << 3)];
        oacc[dt] = mfma16(pf, vf, oacc[dt]);
      }
    }
  };

  s16x8 kva = *(const s16x8*)&Kb[(size_t)sr * NDH + sc];
  s16x8 kvb = *(const s16x8*)&Kb[(size_t)(sr + 32) * NDH + sc];
  s16x8 vva = *(const s16x8*)&Vb[(size_t)sr * NDH + sc];
  s16x8 vvb = *(const s16x8*)&Vb[(size_t)(sr + 32) * NDH + sc];

  for (int kt = 0; kt <= ktmax; ++kt) {
    __syncthreads();
    *(s16x8*)&Ks[sr * 64 + (sc ^ ((sr & 7) << 3))] = kva;
    *(s16x8*)&Ks[(sr + 32) * 64 + (sc ^ ((sr & 7) << 3))] = kvb;
    #pragma unroll
    for (int e = 0; e < 8; ++e)
      Vt[(sc + e) * 64 + (sr ^ ((((tid & 7) ^ e)) << 3))] = (u16)vva[e];
    #pragma unroll
    for (int e = 0; e < 8; ++e)
      Vt[(sc + e) * 64 + ((sr + 32) ^ ((((tid & 7) ^ e)) << 3))] = (u16)vvb[e];
    __syncthreads();

    if (kt < ktmax) {
      const u16* Kn = Kb + (size_t)(kt + 1) * 64 * NDH;
      const u16* Vn = Vb + (size_t)(kt + 1) * 64 * NDH;
      kva = *(const s16x8*)&Kn[(size_t)sr * NDH + sc];
      kvb = *(const s16x8*)&Kn[(size_t)(sr + 32) * NDH + sc];
      vva = *(const s16x8*)&Vn[(size_t)sr * NDH + sc];
      vvb = *(const s16x8*)&Vn[(size_t)(sr + 32) * NDH + sc];
    }

    do_strip(q1a, q1b, oacc1, m1, l1, kt == si1);
    if (kt <= si0) do_strip(q0a, q0b, oacc0, m0, l0, kt == si0);
  }

  {
    float lv[4];
    #pragma unroll
    for (int r = 0; r < 4; ++r) lv[r] = 1.f / __shfl(l0, lg * 4 + r);
    #pragma unroll
    for (int dt = 0; dt < 4; ++dt)
      #pragma unroll
      for (int r = 0; r < 4; ++r) {
        const int qg = q00 + w * 16 + lg * 4 + r;
        O[((size_t)b * NT + qg) * ND + h * NDH + dt * 16 + lm] = f2b(oacc0[dt][r] * lv[r]);
      }
  }
  {
    float lv[4];
    #pragma unroll
    for (int r = 0; r < 4; ++r) lv[r] = 1.f / __shfl(l1, lg * 4 + r);
    #pragma unroll
    for (int dt = 0; dt < 4; ++dt)
      #pragma unroll
      for (int r = 0; r < 4; ++r) {
        const int qg = q01 + w * 16 + lg * 4 + r;
        O[((size_t)b * NT + qg) * ND + h * NDH + dt * 16 + lm] = f2b(oacc1[dt][r] * lv[r]);
      }
  }
}

// ---------------- launch ----------------
extern "C" void kernel_launch(void* const* d_in, const int* in_sizes, int n_in,
                              void* d_out, int out_size, void* d_ws, size_t ws_size,
                              hipStream_t stream)
{
  const float* x      = (const float*)d_in[0];
  const float* ln1_g  = (const float*)d_in[1];
  const float* ln1_b  = (const float*)d_in[2];
  const float* w_qkv  = (const float*)d_in[3];
  const float* b_qkv  = (const float*)d_in[4];
  const float* w_proj = (const float*)d_in[5];
  const float* b_proj = (const float*)d_in[6];
  const float* ln2_g  = (const float*)d_in[7];
  const float* ln2_b  = (const float*)d_in[8];
  const float* w_ff1  = (const float*)d_in[9];
  const float* b_ff1  = (const float*)d_in[10];
  const float* w_ff2  = (const float*)d_in[11];
  const float* b_ff2  = (const float*)d_in[12];

  char* ws = (char*)d_ws;
  u16*   wt_qkv = (u16*)(ws + 0);          //  2304x768 bf16
  u16*   wt_proj= (u16*)(ws + 3538944);    //   768x768
  u16*   wt_ff1 = (u16*)(ws + 4718592);    //  3072x768
  u16*   wt_ff2 = (u16*)(ws + 9437184);    //   768x3072
  u16*   hbuf   = (u16*)(ws + 14155776);   //  8192x768 bf16 (LN1 out)
  u16*   qbuf   = (u16*)(ws + 26738688);   //  [B,H,T,DH]
  u16*   kbuf   = (u16*)(ws + 39321600);
  u16*   vbuf   = (u16*)(ws + 51904512);
  u16*   aobuf  = (u16*)(ws + 64487424);   //  8192x768 bf16 (attn out)
  float* x1     = (float*)(ws + 77070336); //  8192x768 fp32
  u16*   h2buf  = (u16*)(ws + 102236160);  //  8192x768 bf16 (LN2 out)
  u16*   ff1buf = hbuf;                    //  8192x3072 bf16, aliases h/q/k/v (dead by then)

  pre_kernel<<<6912 + NM, 256, 0, stream>>>(w_qkv, w_proj, w_ff1, w_ff2,
                                            wt_qkv, wt_proj, wt_ff1, wt_ff2,
                                            x, ln1_g, ln1_b, hbuf);
  gemm_bt<0,128><<<dim3(NM/128, 2304/128), 256, 0, stream>>>(hbuf, wt_qkv, b_qkv, nullptr,
                                                             qbuf, kbuf, vbuf, NM, 2304, ND);
  attn_kernel<<<dim3(NB*NH, 16), 256, 0, stream>>>(qbuf, kbuf, vbuf, aobuf);
  gemm_bt<1,64><<<dim3(NM/64, ND/128), 256, 0, stream>>>(aobuf, wt_proj, b_proj, x,
                                                         x1, nullptr, nullptr, NM, ND, ND);
  ln_kernel<<<NM, 256, 0, stream>>>(x1, ln2_g, ln2_b, h2buf);
  gemm_wide<<<dim3(NM/128, NFF/256), 512, 0, stream>>>(h2buf, wt_ff1, b_ff1, ff1buf, ND);
  gemm_bt<3,64><<<dim3(NM/64, ND/128), 256, 0, stream>>>(ff1buf, wt_ff2, b_ff2, x1,
                                                         d_out, nullptr, nullptr, NM, ND, NFF);
}

// Round 18
// 281.562 us; speedup vs baseline: 1.0201x; 1.0196x over previous
//
#include <hip/hip_runtime.h>
#include <cstdint>
#include <cstddef>

typedef unsigned short u16;
typedef unsigned int u32;
typedef __attribute__((ext_vector_type(8))) short s16x8;
typedef __attribute__((ext_vector_type(4))) float f32x4;

#define NB 4
#define NT 2048
#define ND 768
#define NH 12
#define NDH 64
#define NFF 3072
#define NM (NB*NT)   // 8192 rows

__device__ __forceinline__ u16 f2b(float f){
  union { float f; unsigned u; } c; c.f = f;
  unsigned r = c.u + 0x7fffu + ((c.u >> 16) & 1u);
  return (u16)(r >> 16);
}

__device__ __forceinline__ f32x4 mfma16(s16x8 a, s16x8 b, f32x4 c){
  return __builtin_amdgcn_mfma_f32_16x16x32_bf16(a, b, c, 0, 0, 0);
}

// async global->LDS, 16B per lane. LDS dest = wave-uniform base + lane*16.
__device__ __forceinline__ void stage16(u16* lds, const u16* g){
  __builtin_amdgcn_global_load_lds(
      (const __attribute__((address_space(1))) unsigned int*)g,
      (__attribute__((address_space(3))) unsigned int*)lds,
      16, 0, 0);
}

// erf via A&S 7.1.26 (|err|<1.5e-7): 1 expf + ~12 fma, ~3x cheaper than libm erff
__device__ __forceinline__ float gelu_f(float v){
  const float x = v * 0.70710678118654752f;
  const float ax = fabsf(x);
  const float t = 1.f / (1.f + 0.3275911f * ax);
  const float y = t * (0.254829592f + t * (-0.284496736f + t * (1.421413741f
                + t * (-1.453152027f + t * 1.061405429f))));
  float er = 1.f - y * __expf(-ax * ax);
  er = copysignf(er, x);
  return 0.5f * v * (1.f + er);
}

// ---------------- merged transpose + fp32->bf16 convert for all 4 weights ----------------
__global__ __launch_bounds__(256) void transpose_all(
    const float* __restrict__ w_qkv, const float* __restrict__ w_proj,
    const float* __restrict__ w_ff1, const float* __restrict__ w_ff2,
    u16* __restrict__ o_qkv, u16* __restrict__ o_proj,
    u16* __restrict__ o_ff1, u16* __restrict__ o_ff2)
{
  int bid = blockIdx.x;
  const float* in; u16* out; int K, N, nx;
  if (bid < 1728)      { in = w_qkv;  out = o_qkv;  K = 768;  N = 2304; nx = 72; }
  else if ((bid -= 1728) < 576)  { in = w_proj; out = o_proj; K = 768;  N = 768;  nx = 24; }
  else if ((bid -= 576) < 2304)  { in = w_ff1;  out = o_ff1;  K = 768;  N = 3072; nx = 96; }
  else { bid -= 2304;              in = w_ff2;  out = o_ff2;  K = 3072; N = 768;  nx = 24; }
  const int n0 = (bid % nx) * 32, k0 = (bid / nx) * 32;

  __shared__ float tile[32][33];
  const int tx = threadIdx.x, ty = threadIdx.y; // 32 x 8
  #pragma unroll
  for (int i = 0; i < 32; i += 8)
    tile[ty + i][tx] = in[(size_t)(k0 + ty + i) * N + n0 + tx];
  __syncthreads();
  #pragma unroll
  for (int i = 0; i < 32; i += 8)
    out[(size_t)(n0 + ty + i) * K + k0 + tx] = f2b(tile[tx][ty + i]);
}

// ---------------- LayerNorm (row = 768), fp32 in -> bf16 out ----------------
__global__ __launch_bounds__(256) void ln_kernel(
    const float* __restrict__ x, const float* __restrict__ g,
    const float* __restrict__ b, u16* __restrict__ out)
{
  const int row = blockIdx.x;
  const int t = threadIdx.x;
  const float* xr = x + (size_t)row * ND;
  float v0 = xr[t], v1 = xr[t + 256], v2 = xr[t + 512];
  float s = v0 + v1 + v2;
  float ss = v0*v0 + v1*v1 + v2*v2;
  #pragma unroll
  for (int o = 32; o; o >>= 1) { s += __shfl_xor(s, o, 64); ss += __shfl_xor(ss, o, 64); }
  __shared__ float red[8];
  const int w = t >> 6;
  if ((t & 63) == 0) { red[w] = s; red[4 + w] = ss; }
  __syncthreads();
  s  = red[0] + red[1] + red[2] + red[3];
  ss = red[4] + red[5] + red[6] + red[7];
  const float mu = s * (1.f / ND);
  const float var = ss * (1.f / ND) - mu * mu;
  const float rinv = rsqrtf(var + 1e-5f);
  u16* orow = out + (size_t)row * ND;
  orow[t]       = f2b((v0 - mu) * rinv * g[t]       + b[t]);
  orow[t + 256] = f2b((v1 - mu) * rinv * g[t + 256] + b[t + 256]);
  orow[t + 512] = f2b((v2 - mu) * rinv * g[t + 512] + b[t + 512]);
}

// ---------------- GEMM: counted-vmcnt pipeline, triple-buffer LDS, chunk swizzle ----------------
// (round-8/11/13 measured configuration — best known)
// C[M][N] = A[M][K] * Bt[N][K]^T + bias, fused epilogue. BM in {128, 64}, BN = 128.
// EPI 0: qkv split-scatter to [B,H,T,DH] bf16 (o0=q scaled by 0.125, o1=k, o2=v)
// EPI 1: + res (x) -> fp32 o0
// EPI 2: gelu -> bf16 o0
// EPI 3: + res (x1) -> fp32 o0
template<int EPI, int BM>
__global__ __launch_bounds__(256, (BM == 128) ? 3 : 4) void gemm_bt(
    const u16* __restrict__ A, const u16* __restrict__ Bt,
    const float* __restrict__ bias, const float* __restrict__ res,
    void* __restrict__ o0, void* __restrict__ o1, void* __restrict__ o2,
    const int M, const int N, const int K)
{
  constexpr int MI = BM / 64;
  __shared__ u16 As[3][BM * 32];
  __shared__ u16 Bs[3][128 * 32];
  const int tid = threadIdx.x;
  const int lane = tid & 63, wid = tid >> 6;
  const int wr = wid >> 1, wc = wid & 1;
  const int lg = lane >> 4, lm = lane & 15;
  const int bm = blockIdx.x * BM, bn = blockIdx.y * 128;

  f32x4 acc[2 * MI][4] = {};

  const int srow = tid >> 2;
  const int schunk = (tid & 3) ^ ((tid >> 3) & 3);
  const u16* ApT = A  + (size_t)(bm + srow) * K + schunk * 8;
  const u16* BpT = Bt + (size_t)(bn + srow) * K + schunk * 8;
  const size_t rs64 = (size_t)64 * K;
  const int woff = wid * 512;
  const int fswz = (lm >> 1) & 3;

  const int nt = K >> 5;

  #pragma unroll
  for (int p = 0; p < 2; ++p) {
    const int k0 = p << 5;
    stage16(&As[p][woff], ApT + k0);
    if (BM == 128) stage16(&As[p][woff + 2048], ApT + rs64 + k0);
    stage16(&Bs[p][woff],        BpT + k0);
    stage16(&Bs[p][woff + 2048], BpT + rs64 + k0);
  }

  for (int t = 0; t < nt; ++t) {
    if (t < nt - 1) {
      if (BM == 128) asm volatile("s_waitcnt vmcnt(4)" ::: "memory");
      else           asm volatile("s_waitcnt vmcnt(3)" ::: "memory");
    } else {
      asm volatile("s_waitcnt vmcnt(0)" ::: "memory");
    }
    __builtin_amdgcn_s_barrier();
    __builtin_amdgcn_sched_barrier(0);
    if (t + 2 < nt) {
      const int k0 = (t + 2) << 5;
      const int wb = (t + 2) % 3;
      stage16(&As[wb][woff], ApT + k0);
      if (BM == 128) stage16(&As[wb][woff + 2048], ApT + rs64 + k0);
      stage16(&Bs[wb][woff],        BpT + k0);
      stage16(&Bs[wb][woff + 2048], BpT + rs64 + k0);
    }
    __builtin_amdgcn_sched_barrier(0);
    const int rb = t % 3;
    s16x8 af[2 * MI], bf[4];
    #pragma unroll
    for (int i = 0; i < 2 * MI; i++)
      af[i] = *(const s16x8*)&As[rb][(wr * (BM / 2) + i * 16 + lm) * 32 + ((lg ^ fswz) * 8)];
    #pragma unroll
    for (int j = 0; j < 4; j++)
      bf[j] = *(const s16x8*)&Bs[rb][(wc * 64 + j * 16 + lm) * 32 + ((lg ^ fswz) * 8)];
    #pragma unroll
    for (int i = 0; i < 2 * MI; i++)
      #pragma unroll
      for (int j = 0; j < 4; j++)
        acc[i][j] = mfma16(af[i], bf[j], acc[i][j]);
  }

  #pragma unroll
  for (int i = 0; i < 2 * MI; i++)
    #pragma unroll
    for (int j = 0; j < 4; j++) {
      const int col = bn + wc * 64 + j * 16 + lm;
      const float bb = bias[col];
      #pragma unroll
      for (int r = 0; r < 4; r++) {
        const int row = bm + wr * (BM / 2) + i * 16 + lg * 4 + r;
        float v = acc[i][j][r] + bb;
        if (EPI == 0) {
          u16* dst; int rem;
          if (col < ND)            { dst = (u16*)o0; rem = col; v *= 0.125f; }
          else if (col < 2 * ND)   { dst = (u16*)o1; rem = col - ND; }
          else                     { dst = (u16*)o2; rem = col - 2 * ND; }
          const int hh = rem >> 6, dh = rem & 63;
          const int bb2 = row >> 11, tt = row & 2047;
          dst[(((size_t)bb2 * NH + hh) * NT + tt) * NDH + dh] = f2b(v);
        } else if (EPI == 1) {
          ((float*)o0)[(size_t)row * ND + col] = v + res[(size_t)row * ND + col];
        } else if (EPI == 2) {
          ((u16*)o0)[(size_t)row * NFF + col] = f2b(gelu_f(v));
        } else {
          ((float*)o0)[(size_t)row * ND + col] = v + res[(size_t)row * ND + col];
        }
      }
    }
}

// ---------------- Flash attention, causal, swapped-QK^T, MERGED complementary strips ----------------
// Q pre-scaled by 0.125. Q,K,V: [B,H,T,DH] bf16. O: [B,T,D] bf16.
// Block: 256 thr (4 waves), strips si0 = p and si1 = 31-p processed in ONE pass over
// kv tiles kt = 0..31-p: strip1 active every step, strip0 while kt <= p. K/V staging
// SHARED by both strips; steps/block 33 -> 32-p; dual independent chains -> ILP.
// Grid: (bh, pair) with bh FASTEST -> 16 blocks sharing a head's K/V on one XCD.
__global__ __launch_bounds__(256,2) void attn_kernel(
    const u16* __restrict__ Q, const u16* __restrict__ Kg,
    const u16* __restrict__ V, u16* __restrict__ O)
{
  const int p  = blockIdx.y;        // 0..15
  const int bh = blockIdx.x;        // b*H + h  (fastest-varying)
  const int b = bh / NH, h = bh % NH;
  const int tid = threadIdx.x;
  const int lane = tid & 63, w = tid >> 6;
  const int lg = lane >> 4, lm = lane & 15;
  const int sr = tid >> 3;          // 0..31 (staging row)
  const int sc = (tid & 7) * 8;     // 0..56 (staging col)

  __shared__ u16 Ks[64 * 64];
  __shared__ u16 Vt[64 * 64];
  __shared__ u16 Ps[4][16 * 64];

  const u16* Qb = Q  + (size_t)bh * NT * NDH;
  const u16* Kb = Kg + (size_t)bh * NT * NDH;
  const u16* Vb = V  + (size_t)bh * NT * NDH;

  const int si0 = p, si1 = 31 - p;
  const int q00 = si0 * 64, q01 = si1 * 64;
  const int ktmax = si1;

  const s16x8 q0a = *(const s16x8*)&Qb[(size_t)(q00 + w * 16 + lm) * NDH + lg * 8];
  const s16x8 q0b = *(const s16x8*)&Qb[(size_t)(q00 + w * 16 + lm) * NDH + 32 + lg * 8];
  const s16x8 q1a = *(const s16x8*)&Qb[(size_t)(q01 + w * 16 + lm) * NDH + lg * 8];
  const s16x8 q1b = *(const s16x8*)&Qb[(size_t)(q01 + w * 16 + lm) * NDH + 32 + lg * 8];

  f32x4 oacc0[4] = {}, oacc1[4] = {};
  float m0 = -INFINITY, l0 = 0.f, m1 = -INFINITY, l1 = 0.f;

  auto do_strip = [&](const s16x8& qa, const s16x8& qb, f32x4* oacc,
                      float& m, float& l, bool diag) {
    f32x4 sv[4];
    #pragma unroll
    for (int n = 0; n < 4; ++n) {
      const int krow = (n * 16 + lm) * 64;
      const int swz = (lm & 7) << 3;
      s16x8 kf0 = *(const s16x8*)&Ks[krow + ((lg * 8) ^ swz)];
      s16x8 kf1 = *(const s16x8*)&Ks[krow + ((32 + lg * 8) ^ swz)];
      f32x4 s4 = {};
      s4 = mfma16(kf0, qa, s4);
      s4 = mfma16(kf1, qb, s4);
      sv[n] = s4;
    }
    if (diag) {
      #pragma unroll
      for (int n = 0; n < 4; ++n)
        #pragma unroll
        for (int r = 0; r < 4; ++r)
          if (n * 16 + lg * 4 + r > w * 16 + lm) sv[n][r] = -INFINITY;
    }
    float mx = -INFINITY;
    #pragma unroll
    for (int n = 0; n < 4; ++n)
      #pragma unroll
      for (int r = 0; r < 4; ++r) mx = fmaxf(mx, sv[n][r]);
    mx = fmaxf(mx, __shfl_xor(mx, 16));
    mx = fmaxf(mx, __shfl_xor(mx, 32));
    const float mnew = fmaxf(m, mx);
    const float alpha = __expf(m - mnew);
    m = mnew;

    float rs = 0.f;
    u32 pk[4][2];
    #pragma unroll
    for (int n = 0; n < 4; ++n) {
      const float p0 = __expf(sv[n][0] - mnew);
      const float p1 = __expf(sv[n][1] - mnew);
      const float p2 = __expf(sv[n][2] - mnew);
      const float p3 = __expf(sv[n][3] - mnew);
      rs += (p0 + p1) + (p2 + p3);
      pk[n][0] = (u32)f2b(p0) | ((u32)f2b(p1) << 16);
      pk[n][1] = (u32)f2b(p2) | ((u32)f2b(p3) << 16);
    }
    rs += __shfl_xor(rs, 16);
    rs += __shfl_xor(rs, 32);
    l = l * alpha + rs;

    #pragma unroll
    for (int n = 0; n < 4; ++n) {
      const int idx0 = lm * 64 + ((n * 16 + lg * 4) ^ ((lm & 7) << 3));
      *(u32*)&Ps[w][idx0] = pk[n][0];
      *(u32*)&Ps[w][idx0 + 2] = pk[n][1];
    }

    float av[4];
    #pragma unroll
    for (int r = 0; r < 4; ++r) av[r] = __shfl(alpha, lg * 4 + r);
    #pragma unroll
    for (int d = 0; d < 4; ++d)
      #pragma unroll
      for (int r = 0; r < 4; ++r) oacc[d][r] *= av[r];

    #pragma unroll
    for (int kh = 0; kh < 2; ++kh) {
      const s16x8 pf = *(const s16x8*)&Ps[w][lm * 64 + ((kh * 32 + lg * 8) ^ ((lm & 7) << 3))];
      #pragma unroll
      for (int dt = 0; dt < 4; ++dt) {
        const int g = ((2 * dt + (lm >> 3)) ^ (lm & 7)) & 7;
        const s16x8 vf = *(const s16x8*)&Vt[(dt * 16 + lm) * 64 + (((kh * 4 + lg) ^ g) << 3)];
        oacc[dt] = mfma16(pf, vf, oacc[dt]);
      }
    }
  };

  // prefetch tile 0
  s16x8 kva = *(const s16x8*)&Kb[(size_t)sr * NDH + sc];
  s16x8 kvb = *(const s16x8*)&Kb[(size_t)(sr + 32) * NDH + sc];
  s16x8 vva = *(const s16x8*)&Vb[(size_t)sr * NDH + sc];
  s16x8 vvb = *(const s16x8*)&Vb[(size_t)(sr + 32) * NDH + sc];

  for (int kt = 0; kt <= ktmax; ++kt) {
    __syncthreads();
    *(s16x8*)&Ks[sr * 64 + (sc ^ ((sr & 7) << 3))] = kva;
    *(s16x8*)&Ks[(sr + 32) * 64 + (sc ^ ((sr & 7) << 3))] = kvb;
    #pragma unroll
    for (int e = 0; e < 8; ++e)
      Vt[(sc + e) * 64 + (sr ^ ((((tid & 7) ^ e)) << 3))] = (u16)vva[e];
    #pragma unroll
    for (int e = 0; e < 8; ++e)
      Vt[(sc + e) * 64 + ((sr + 32) ^ ((((tid & 7) ^ e)) << 3))] = (u16)vvb[e];
    __syncthreads();

    if (kt < ktmax) {
      const u16* Kn = Kb + (size_t)(kt + 1) * 64 * NDH;
      const u16* Vn = Vb + (size_t)(kt + 1) * 64 * NDH;
      kva = *(const s16x8*)&Kn[(size_t)sr * NDH + sc];
      kvb = *(const s16x8*)&Kn[(size_t)(sr + 32) * NDH + sc];
      vva = *(const s16x8*)&Vn[(size_t)sr * NDH + sc];
      vvb = *(const s16x8*)&Vn[(size_t)(sr + 32) * NDH + sc];
    }

    do_strip(q1a, q1b, oacc1, m1, l1, kt == si1);
    if (kt <= si0) do_strip(q0a, q0b, oacc0, m0, l0, kt == si0);
  }

  {
    float lv[4];
    #pragma unroll
    for (int r = 0; r < 4; ++r) lv[r] = 1.f / __shfl(l0, lg * 4 + r);
    #pragma unroll
    for (int dt = 0; dt < 4; ++dt)
      #pragma unroll
      for (int r = 0; r < 4; ++r) {
        const int qg = q00 + w * 16 + lg * 4 + r;
        O[((size_t)b * NT + qg) * ND + h * NDH + dt * 16 + lm] = f2b(oacc0[dt][r] * lv[r]);
      }
  }
  {
    float lv[4];
    #pragma unroll
    for (int r = 0; r < 4; ++r) lv[r] = 1.f / __shfl(l1, lg * 4 + r);
    #pragma unroll
    for (int dt = 0; dt < 4; ++dt)
      #pragma unroll
      for (int r = 0; r < 4; ++r) {
        const int qg = q01 + w * 16 + lg * 4 + r;
        O[((size_t)b * NT + qg) * ND + h * NDH + dt * 16 + lm] = f2b(oacc1[dt][r] * lv[r]);
      }
  }
}

// ---------------- launch ----------------
extern "C" void kernel_launch(void* const* d_in, const int* in_sizes, int n_in,
                              void* d_out, int out_size, void* d_ws, size_t ws_size,
                              hipStream_t stream)
{
  const float* x      = (const float*)d_in[0];
  const float* ln1_g  = (const float*)d_in[1];
  const float* ln1_b  = (const float*)d_in[2];
  const float* w_qkv  = (const float*)d_in[3];
  const float* b_qkv  = (const float*)d_in[4];
  const float* w_proj = (const float*)d_in[5];
  const float* b_proj = (const float*)d_in[6];
  const float* ln2_g  = (const float*)d_in[7];
  const float* ln2_b  = (const float*)d_in[8];
  const float* w_ff1  = (const float*)d_in[9];
  const float* b_ff1  = (const float*)d_in[10];
  const float* w_ff2  = (const float*)d_in[11];
  const float* b_ff2  = (const float*)d_in[12];

  char* ws = (char*)d_ws;
  u16*   wt_qkv = (u16*)(ws + 0);          //  2304x768 bf16
  u16*   wt_proj= (u16*)(ws + 3538944);    //   768x768
  u16*   wt_ff1 = (u16*)(ws + 4718592);    //  3072x768
  u16*   wt_ff2 = (u16*)(ws + 9437184);    //   768x3072
  u16*   hbuf   = (u16*)(ws + 14155776);   //  8192x768 bf16 (LN1 out)
  u16*   qbuf   = (u16*)(ws + 26738688);   //  [B,H,T,DH]
  u16*   kbuf   = (u16*)(ws + 39321600);
  u16*   vbuf   = (u16*)(ws + 51904512);
  u16*   aobuf  = (u16*)(ws + 64487424);   //  8192x768 bf16 (attn out)
  float* x1     = (float*)(ws + 77070336); //  8192x768 fp32
  u16*   h2buf  = (u16*)(ws + 102236160);  //  8192x768 bf16 (LN2 out)
  u16*   ff1buf = hbuf;                    //  8192x3072 bf16, aliases h/q/k/v (dead by then)

  transpose_all<<<6912, dim3(32,8), 0, stream>>>(w_qkv, w_proj, w_ff1, w_ff2,
                                                 wt_qkv, wt_proj, wt_ff1, wt_ff2);

  ln_kernel<<<NM, 256, 0, stream>>>(x, ln1_g, ln1_b, hbuf);
  gemm_bt<0,128><<<dim3(NM/128, 2304/128), 256, 0, stream>>>(hbuf, wt_qkv, b_qkv, nullptr,
                                                             qbuf, kbuf, vbuf, NM, 2304, ND);
  attn_kernel<<<dim3(NB*NH, 16), 256, 0, stream>>>(qbuf, kbuf, vbuf, aobuf);
  gemm_bt<1,64><<<dim3(NM/64, ND/128), 256, 0, stream>>>(aobuf, wt_proj, b_proj, x,
                                                         x1, nullptr, nullptr, NM, ND, ND);
  ln_kernel<<<NM, 256, 0, stream>>>(x1, ln2_g, ln2_b, h2buf);
  gemm_bt<2,128><<<dim3(NM/128, NFF/128), 256, 0, stream>>>(h2buf, wt_ff1, b_ff1, nullptr,
                                                            ff1buf, nullptr, nullptr, NM, NFF, ND);
  gemm_bt<3,64><<<dim3(NM/64, ND/128), 256, 0, stream>>>(ff1buf, wt_ff2, b_ff2, x1,
                                                         d_out, nullptr, nullptr, NM, ND, NFF);
}